// Round 5
// baseline (149.848 us; speedup 1.0000x reference)
//
#include <hip/hip_runtime.h>
#include <hip/hip_bf16.h>

#define B_ 4
#define N_ 4096
#define D_ 128
#define QSEG 8

typedef __bf16 bf16x8 __attribute__((ext_vector_type(8)));
typedef float f32x4 __attribute__((ext_vector_type(4)));

// alpha = log2(e) / sqrt(128), folded into Qp at conversion time
#define ALPHA 0.12752361680972262f

// ws layout (all fragment-linear packed, 16 B per (tile,frag,lane) chunk):
//   Qp : bf16 [B][256 qstep][4 f][64 lane][8]   @ 0      (4 MiB, alpha-scaled)
//   Kp : bf16 [B][128 kb][8 slot=f*2+ab][64][8] @ 4 MiB  (permuted-key frag order)
//   Vp : bf16 [B][128 kb][8 ds][64][8]          @ 8 MiB  (1/l folded in place)
//   l    : f32 [B][N]                           @ 12 MiB
#define OFF_KP   (4u << 20)
#define OFF_VP   (8u << 20)
#define OFF_L    (12u << 20)

// ---------------------------------------------------------------------------
// Kernel A: pack Q*alpha, K (permuted key order), V-transpose into fragment-
// linear layouts. Blocks 2560..2575 zero l. UNCHANGED from R4.
// ---------------------------------------------------------------------------
__global__ __launch_bounds__(256) void cvt_kernel(
    const float* __restrict__ q, const float* __restrict__ k,
    const float* __restrict__ v,
    __bf16* __restrict__ qp, __bf16* __restrict__ kp, __bf16* __restrict__ vp,
    float* __restrict__ l)
{
    __shared__ float vl[32 * 129];   // 16.5 KiB (V section only)

    int bid = blockIdx.x;
    int tid = threadIdx.x;
    if (bid < 2048) {
        int g = (bid & 1023) * 256 + tid;   // 0..262143 within section
        int lane = g & 63;
        int l15 = lane & 15, quad = lane >> 4;
        if (bid < 1024) {
            int f = (g >> 6) & 3;
            int qstep = (g >> 8) & 255;
            int b = g >> 16;
            const float* src = q + ((size_t)(b * N_ + qstep * 16 + l15) * D_ + (f * 4 + quad) * 8);
            float4 x0 = *(const float4*)src;
            float4 x1 = *(const float4*)(src + 4);
            bf16x8 y;
            y[0] = (__bf16)(x0.x * ALPHA); y[1] = (__bf16)(x0.y * ALPHA);
            y[2] = (__bf16)(x0.z * ALPHA); y[3] = (__bf16)(x0.w * ALPHA);
            y[4] = (__bf16)(x1.x * ALPHA); y[5] = (__bf16)(x1.y * ALPHA);
            y[6] = (__bf16)(x1.z * ALPHA); y[7] = (__bf16)(x1.w * ALPHA);
            ((bf16x8*)qp)[g] = y;
        } else {
            int slot = (g >> 6) & 7;
            int kb = (g >> 9) & 127;
            int b = g >> 16;
            int f = slot >> 1, ab = slot & 1;
            int row = kb * 32 + (l15 >> 2) * 8 + (l15 & 3) + ab * 4;
            const float* src = k + ((size_t)(b * N_ + row) * D_ + (f * 4 + quad) * 8);
            float4 x0 = *(const float4*)src;
            float4 x1 = *(const float4*)(src + 4);
            bf16x8 y;
            y[0] = (__bf16)x0.x; y[1] = (__bf16)x0.y; y[2] = (__bf16)x0.z; y[3] = (__bf16)x0.w;
            y[4] = (__bf16)x1.x; y[5] = (__bf16)x1.y; y[6] = (__bf16)x1.z; y[7] = (__bf16)x1.w;
            ((bf16x8*)kp)[g] = y;
        }
    } else if (bid < 2560) {
        int vb = bid - 2048;                // 0..511: one (b, kb) tile
        int b = vb >> 7, kb = vb & 127;
        const float4* src = (const float4*)(v + (size_t)(b * N_ + kb * 32) * D_);
#pragma unroll
        for (int rep = 0; rep < 4; ++rep) {
            int i = rep * 256 + tid;
            int row = i >> 5, c4 = i & 31;
            float4 x = src[row * 32 + c4];
            float* dst = &vl[row * 129 + c4 * 4];
            dst[0] = x.x; dst[1] = x.y; dst[2] = x.z; dst[3] = x.w;
        }
        __syncthreads();
#pragma unroll
        for (int rep = 0; rep < 2; ++rep) {
            int ci = rep * 256 + tid;       // 0..511
            int ds = ci >> 6, ln = ci & 63;
            int quad = ln >> 4, l15 = ln & 15;
            bf16x8 y;
#pragma unroll
            for (int j = 0; j < 8; ++j)
                y[j] = (__bf16)vl[(quad * 8 + j) * 129 + ds * 16 + l15];
            ((bf16x8*)vp)[(((size_t)(b * 128 + kb) * 8) + ds) * 64 + ln] = y;
        }
    } else {
        // zero l: 16 blocks x 256 threads x float4 = 16384 floats
        int i = (bid - 2560) * 256 + tid;
        ((f32x4*)l)[i] = (f32x4){0.f, 0.f, 0.f, 0.f};
    }
}

// ---------------------------------------------------------------------------
// Kernel B: column stats, barrier-free. K-fragments in regs (as before);
// Q streamed global->reg per wave (no LDS, no __syncthreads). 4 blk/CU,
// 16 waves/CU free-running. XCD swizzle: batch b pinned to XCD pair so
// Qp/Kp slices are L2-resident.
// ---------------------------------------------------------------------------
__global__ __launch_bounds__(256, 4) void stats_kernel(
    const __bf16* __restrict__ qp, const __bf16* __restrict__ kp,
    float* __restrict__ l)
{
    int x = blockIdx.x;                   // 1024 blocks
    int xcd = x & 7;
    int i = x >> 3;                       // 0..127
    int b = xcd >> 1;
    int qseg = (xcd & 1) * 4 + (i & 3);   // 0..7
    int kb4 = i >> 2;                     // 0..31

    int w = threadIdx.x >> 6;
    int lane = threadIdx.x & 63;
    int quad = lane >> 4, l15 = lane & 15;
    int kb = kb4 * 4 + w;

    const bf16x8* kc = (const bf16x8*)kp;
    const bf16x8* qc8 = (const bf16x8*)qp;

    bf16x8 af[2][4];
#pragma unroll
    for (int ab = 0; ab < 2; ++ab)
#pragma unroll
        for (int f = 0; f < 4; ++f)
            af[ab][f] = kc[(((size_t)(b * 128 + kb) * 8) + f * 2 + ab) * 64 + lane];

    int qs0 = qseg * 32;                  // this block's 32 q-steps
    const bf16x8* pQ = qc8 + ((size_t)(b * 256 + qs0) * 4) * 64 + lane;

    float ps[8];
#pragma unroll
    for (int s = 0; s < 8; ++s) ps[s] = 0.f;

#pragma unroll 4
    for (int t = 0; t < 32; ++t) {
        bf16x8 qf[4];
#pragma unroll
        for (int f = 0; f < 4; ++f)
            qf[f] = pQ[(size_t)t * 256 + f * 64];
#pragma unroll
        for (int ab = 0; ab < 2; ++ab) {
            f32x4 acc = {0.f, 0.f, 0.f, 0.f};
#pragma unroll
            for (int f = 0; f < 4; ++f)
                acc = __builtin_amdgcn_mfma_f32_16x16x32_bf16(af[ab][f], qf[f], acc, 0, 0, 0);
#pragma unroll
            for (int r = 0; r < 4; ++r)
                ps[ab * 4 + r] += __builtin_amdgcn_exp2f(acc[r]);
        }
    }
#pragma unroll
    for (int m = 1; m <= 8; m <<= 1)
#pragma unroll
        for (int s = 0; s < 8; ++s)
            ps[s] += __shfl_xor(ps[s], m, 64);
    if (l15 == 0) {
        // permuted C rows: key = kb*32 + quad*8 + ab*4 + r
        float* dst = l + (size_t)b * N_ + kb * 32 + quad * 8;
#pragma unroll
        for (int ab = 0; ab < 2; ++ab)
#pragma unroll
            for (int r = 0; r < 4; ++r)
                atomicAdd(dst + ab * 4 + r, ps[ab * 4 + r]);
    }
}

// ---------------------------------------------------------------------------
// Kernel C2: Vp chunk (b,kb,ds,lane) *= 1/l[...]  UNCHANGED.
// ---------------------------------------------------------------------------
__global__ __launch_bounds__(256) void scalev_kernel(
    const float* __restrict__ l, __bf16* __restrict__ vp)
{
    int i = blockIdx.x * 256 + threadIdx.x;  // chunk index, 262144 total
    int lane = i & 63;
    int kb = (i >> 9) & 127;
    int b = i >> 16;
    int quad = lane >> 4;
    int k0 = kb * 32 + quad * 8;
    const float* lp = l + (size_t)b * N_ + k0;
    float4 a = *(const float4*)lp;
    float4 c = *(const float4*)(lp + 4);
    float r0 = __builtin_amdgcn_rcpf(a.x), r1 = __builtin_amdgcn_rcpf(a.y);
    float r2 = __builtin_amdgcn_rcpf(a.z), r3 = __builtin_amdgcn_rcpf(a.w);
    float r4 = __builtin_amdgcn_rcpf(c.x), r5 = __builtin_amdgcn_rcpf(c.y);
    float r6 = __builtin_amdgcn_rcpf(c.z), r7 = __builtin_amdgcn_rcpf(c.w);
    bf16x8 v = ((const bf16x8*)vp)[i];
    bf16x8 o;
    o[0] = (__bf16)((float)v[0] * r0); o[1] = (__bf16)((float)v[1] * r1);
    o[2] = (__bf16)((float)v[2] * r2); o[3] = (__bf16)((float)v[3] * r3);
    o[4] = (__bf16)((float)v[4] * r4); o[5] = (__bf16)((float)v[5] * r5);
    o[6] = (__bf16)((float)v[6] * r6); o[7] = (__bf16)((float)v[7] * r7);
    ((bf16x8*)vp)[i] = o;
}

// ---------------------------------------------------------------------------
// Kernel D: attention, barrier-free KSEG=1. Block = 4 waves, 32 q rows
// shared (bq in regs); wave w owns kb tiles {w, w+4, ..., w+124} and
// streams K/V global->reg, software-pipelined one tile ahead (A/B buffers,
// loads issued one compute-phase before use; compiler vmcnt-per-use gives
// the overlap). No LDS staging, no ds_read, no in-loop __syncthreads.
// XCD swizzle: batch b -> XCD pair, K+V slice (2 MB) L2-resident.
// Epilogue: one LDS round to sum the 4 waves' accumulators, direct store
// to out (no part buffer, no reduce kernel).
// ---------------------------------------------------------------------------
__global__ __launch_bounds__(256, 2) void attn_kernel(
    const __bf16* __restrict__ qp, const __bf16* __restrict__ kp,
    const __bf16* __restrict__ vp, float* __restrict__ out)
{
    __shared__ f32x4 red[4][16][64];      // 64 KiB cross-wave reduction

    int x = blockIdx.x;                   // 512 blocks
    int xcd = x & 7;
    int b = xcd >> 1;
    int qblk = (xcd & 1) * 64 + (x >> 3); // 0..127

    int w = threadIdx.x >> 6;
    int lane = threadIdx.x & 63;
    int quad = lane >> 4, l15 = lane & 15;

    const bf16x8* qc8 = (const bf16x8*)qp;
    const bf16x8* kc = (const bf16x8*)kp;
    const bf16x8* vc = (const bf16x8*)vp;

    int qstep0 = qblk * 2;                // block's 32 q rows (2 q-steps)
    bf16x8 bq[2][4];
#pragma unroll
    for (int s = 0; s < 2; ++s)
#pragma unroll
        for (int f = 0; f < 4; ++f)
            bq[s][f] = qc8[((size_t)(b * 256 + qstep0 + s) * 4 + f) * 64 + lane];

    f32x4 oacc[2][8];
#pragma unroll
    for (int s = 0; s < 2; ++s)
#pragma unroll
        for (int d = 0; d < 8; ++d) oacc[s][d] = (f32x4){0.f, 0.f, 0.f, 0.f};

    // wave w's tile t has kb = w + 4t; chunk stride 64, tile stride 2048
    const bf16x8* pK = kc + (size_t)(b * 128 + w) * 512 + lane;
    const bf16x8* pV = vc + (size_t)(b * 128 + w) * 512 + lane;

#define LOADK(dst, tt) _Pragma("unroll") \
    for (int c = 0; c < 8; ++c) dst[c] = pK[(size_t)(tt) * 2048 + c * 64];
#define LOADV(dst, tt) _Pragma("unroll") \
    for (int c = 0; c < 8; ++c) dst[c] = pV[(size_t)(tt) * 2048 + c * 64];

#define QK(kr, pb) _Pragma("unroll") \
    for (int s = 0; s < 2; ++s) { \
        f32x4 accA = {0.f, 0.f, 0.f, 0.f}; \
        f32x4 accB = {0.f, 0.f, 0.f, 0.f}; \
        _Pragma("unroll") \
        for (int f = 0; f < 4; ++f) { \
            accA = __builtin_amdgcn_mfma_f32_16x16x32_bf16(kr[f * 2 + 0], bq[s][f], accA, 0, 0, 0); \
            accB = __builtin_amdgcn_mfma_f32_16x16x32_bf16(kr[f * 2 + 1], bq[s][f], accB, 0, 0, 0); \
        } \
        pb[s][0] = (__bf16)__builtin_amdgcn_exp2f(accA[0]); \
        pb[s][1] = (__bf16)__builtin_amdgcn_exp2f(accA[1]); \
        pb[s][2] = (__bf16)__builtin_amdgcn_exp2f(accA[2]); \
        pb[s][3] = (__bf16)__builtin_amdgcn_exp2f(accA[3]); \
        pb[s][4] = (__bf16)__builtin_amdgcn_exp2f(accB[0]); \
        pb[s][5] = (__bf16)__builtin_amdgcn_exp2f(accB[1]); \
        pb[s][6] = (__bf16)__builtin_amdgcn_exp2f(accB[2]); \
        pb[s][7] = (__bf16)__builtin_amdgcn_exp2f(accB[3]); \
    }

#define PV(vr, pb) _Pragma("unroll") \
    for (int ds = 0; ds < 8; ++ds) { \
        _Pragma("unroll") \
        for (int s = 0; s < 2; ++s) \
            oacc[s][ds] = __builtin_amdgcn_mfma_f32_16x16x32_bf16(vr[ds], pb[s], oacc[s][ds], 0, 0, 0); \
    }

    bf16x8 kA[8], vA[8], kB[8], vB[8];
    LOADK(kA, 0); LOADV(vA, 0);

    for (int t = 0; t < 32; t += 2) {
        int t2 = (t + 2 < 32) ? t + 2 : 31;
        {
            LOADK(kB, t + 1);             // in flight under QK(A)+PV(A)
            bf16x8 pb[2];
            QK(kA, pb);
            LOADV(vB, t + 1);             // in flight under PV(A)+QK(B)
            PV(vA, pb);
        }
        {
            LOADK(kA, t2);                // in flight under QK(B)+PV(B)
            bf16x8 pb[2];
            QK(kB, pb);
            LOADV(vA, t2);
            PV(vB, pb);
        }
    }
#undef LOADK
#undef LOADV
#undef QK
#undef PV

    // cross-wave reduction (the only barrier in the kernel)
#pragma unroll
    for (int s = 0; s < 2; ++s)
#pragma unroll
        for (int ds = 0; ds < 8; ++ds)
            red[w][s * 8 + ds][lane] = oacc[s][ds];
    __syncthreads();

    int q0 = qblk * 32;
    float* op = out + ((size_t)b * N_ + q0) * D_;
#pragma unroll
    for (int j = 0; j < 4; ++j) {
        int p = w * 4 + j;                // 0..15 = s*8 + ds
        f32x4 sA = red[0][p][lane];
        f32x4 sB = red[1][p][lane];
        f32x4 sC = red[2][p][lane];
        f32x4 sD = red[3][p][lane];
        float4 o4;
        o4.x = sA[0] + sB[0] + sC[0] + sD[0];
        o4.y = sA[1] + sB[1] + sC[1] + sD[1];
        o4.z = sA[2] + sB[2] + sC[2] + sD[2];
        o4.w = sA[3] + sB[3] + sC[3] + sD[3];
        int row = (p >> 3) * 16 + l15;
        int col = (p & 7) * 16 + quad * 4;
        *(float4*)(op + (size_t)row * D_ + col) = o4;
    }
}

extern "C" void kernel_launch(void* const* d_in, const int* in_sizes, int n_in,
                              void* d_out, int out_size, void* d_ws, size_t ws_size,
                              hipStream_t stream) {
    const float* q = (const float*)d_in[0];
    const float* k = (const float*)d_in[1];
    const float* v = (const float*)d_in[2];
    float* out = (float*)d_out;
    char* ws = (char*)d_ws;
    __bf16* qp = (__bf16*)(ws);
    __bf16* kp = (__bf16*)(ws + OFF_KP);
    __bf16* vp = (__bf16*)(ws + OFF_VP);
    float* l    = (float*)(ws + OFF_L);

    hipLaunchKernelGGL(cvt_kernel, dim3(2576), dim3(256), 0, stream, q, k, v, qp, kp, vp, l);
    hipLaunchKernelGGL(stats_kernel, dim3(1024), dim3(256), 0, stream, qp, kp, l);
    hipLaunchKernelGGL(scalev_kernel, dim3(1024), dim3(256), 0, stream, l, vp);
    hipLaunchKernelGGL(attn_kernel, dim3(512), dim3(256), 0, stream, qp, kp, vp, out);
}